// Round 4
// baseline (211.495 us; speedup 1.0000x reference)
//
#include <hip/hip_runtime.h>

#define T_SEQ 256
#define NF 8
#define HID 16
#define NBATCH 4096

// cross-lane value fetch: VALU, no LDS
__device__ __forceinline__ float rdlane(float v, int lane) {
  return __int_as_float(__builtin_amdgcn_readlane(__float_as_int(v), lane));
}
// quad_perm broadcast of lane K within each 4-lane quad (v_mov_b32 dpp, VALU-speed)
template<int K>
__device__ __forceinline__ float qbcast(float v) {
  return __int_as_float(__builtin_amdgcn_update_dpp(
      0, __float_as_int(v), K * 0x55, 0xF, 0xF, true));
}

__device__ __forceinline__ float tanh_fast(float x) {
  // tanh(x) = 2/(1+2^(-2x*log2e)) - 1
  const float e = __builtin_amdgcn_exp2f(-2.8853900817779268f * x);
  return fmaf(2.0f, __builtin_amdgcn_rcpf(1.0f + e), -1.0f);
}

__global__ __launch_bounds__(256, 4)
void lstm_ae_kernel(const float* __restrict__ x,
                    const float* __restrict__ eWih, const float* __restrict__ eWhh,
                    const float* __restrict__ ebih, const float* __restrict__ ebhh,
                    const float* __restrict__ dWih, const float* __restrict__ dWhh,
                    const float* __restrict__ dbih, const float* __restrict__ dbhh,
                    const float* __restrict__ oW, const float* __restrict__ obv,
                    float* __restrict__ out) {
  const int tid = threadIdx.x;
  const int l = tid & 63;                       // lane; one WAVE = one batch element
  int elem = blockIdx.x * 4 + (tid >> 6);
  elem = __builtin_amdgcn_readfirstlane(elem);  // force wave-uniform -> scalar loads of x

  const int k = l & 3;                          // gate: 0=i 1=f 2=g 3=o
  const int u = l >> 2;                         // encoder unit 0..15 (quad u = lanes 4u..4u+3)

  // activation = s*rcp(1+exp2(m*a)) + b : sigmoid (m=-log2e,s=1,b=0), tanh (m=-2log2e,s=2,b=-1)
  const float am = (k == 2) ? -2.8853900817779268f : -1.4426950408889634f;
  const float as = (k == 2) ? 2.0f : 1.0f;
  const float ab = (k == 2) ? -1.0f : 0.0f;

  // ---- encoder weights: lane owns row k*16+u ----
  const int erow = k * 16 + u;
  float wih[8], whh[16];
#pragma unroll
  for (int i = 0; i < 8; ++i) wih[i] = eWih[erow * 8 + i];
#pragma unroll
  for (int i = 0; i < 16; ++i) whh[i] = eWhh[erow * 16 + i];
  const float eb = ebih[erow] + ebhh[erow];

  const float4* xv = (const float4*)(x + (size_t)elem * (T_SEQ * NF));

  float hs[16];                                  // wave-uniform h (SGPRs via readlane)
#pragma unroll
  for (int i = 0; i < 16; ++i) hs[i] = 0.0f;
  float c = 0.0f;

  // x double-buffer: 2 timesteps (16 floats = 4 float4) per chunk, uniform scalar loads
  float4 xc0 = xv[0], xc1 = xv[1], xc2 = xv[2], xc3 = xv[3];

  for (int ch = 0; ch < T_SEQ / 2; ++ch) {
    float4 xn0, xn1, xn2, xn3;
    if (ch < T_SEQ / 2 - 1) {                    // prefetch next 2 timesteps
      xn0 = xv[(ch + 1) * 4 + 0];
      xn1 = xv[(ch + 1) * 4 + 1];
      xn2 = xv[(ch + 1) * 4 + 2];
      xn3 = xv[(ch + 1) * 4 + 3];
    }
#pragma unroll
    for (int s = 0; s < 2; ++s) {
      const float4 xa = s ? xc2 : xc0;
      const float4 xb = s ? xc3 : xc1;
      float a0 = eb, a1 = 0.0f, a2 = 0.0f, a3 = 0.0f;   // 4-way FMA tree
      a0 = fmaf(wih[0], xa.x, a0);
      a1 = fmaf(wih[1], xa.y, a1);
      a2 = fmaf(wih[2], xa.z, a2);
      a3 = fmaf(wih[3], xa.w, a3);
      a0 = fmaf(wih[4], xb.x, a0);
      a1 = fmaf(wih[5], xb.y, a1);
      a2 = fmaf(wih[6], xb.z, a2);
      a3 = fmaf(wih[7], xb.w, a3);
#pragma unroll
      for (int i = 0; i < 4; ++i) {
        a0 = fmaf(whh[4 * i + 0], hs[4 * i + 0], a0);
        a1 = fmaf(whh[4 * i + 1], hs[4 * i + 1], a1);
        a2 = fmaf(whh[4 * i + 2], hs[4 * i + 2], a2);
        a3 = fmaf(whh[4 * i + 3], hs[4 * i + 3], a3);
      }
      const float a = (a0 + a1) + (a2 + a3);
      const float e = __builtin_amdgcn_exp2f(am * a);
      const float act = fmaf(as, __builtin_amdgcn_rcpf(1.0f + e), ab);
      // gather i,f,g,o within the quad (VALU DPP, no LDS)
      const float gi = qbcast<0>(act);
      const float gf = qbcast<1>(act);
      const float gg = qbcast<2>(act);
      const float go = qbcast<3>(act);
      c = fmaf(gf, c, gi * gg);
      const float h = go * tanh_fast(c);
      // h broadcast: 16 readlanes -> wave-uniform SGPRs
#pragma unroll
      for (int i = 0; i < 16; ++i) hs[i] = rdlane(h, 4 * i);
    }
    xc0 = xn0; xc1 = xn1; xc2 = xn2; xc3 = xn3;
  }
  // hs[0..16) = h_enc (uniform)

  // ---- decoder: rows 0-7=i 8-15=f 16-23=g 24-31=o; lane: unit du=l>>3, gate k ----
  const int du = l >> 3;                        // 0..7 ; both quads of the oct duplicate unit du
  const int drow = k * 8 + du;
  float dwhh[8];
#pragma unroll
  for (int i = 0; i < 8; ++i) dwhh[i] = dWhh[drow * 8 + i];
  float cg = dbih[drow] + dbhh[drow];
#pragma unroll
  for (int i = 0; i < 16; ++i) cg = fmaf(dWih[drow * 16 + i], hs[i], cg);  // constant input contrib

  const int yr = l & 7;
  float ow[8];
#pragma unroll
  for (int i = 0; i < 8; ++i) ow[i] = oW[yr * 8 + i];
  const float ob = obv[yr];

  float hd[8];
#pragma unroll
  for (int i = 0; i < 8; ++i) hd[i] = 0.0f;
  float cd = 0.0f;
  float* outp = out + (size_t)elem * (T_SEQ * NF);

  for (int t = 0; t < T_SEQ; ++t) {
    float a0 = cg, a1 = 0.0f, a2 = 0.0f, a3 = 0.0f;
#pragma unroll
    for (int i = 0; i < 2; ++i) {
      a0 = fmaf(dwhh[4 * i + 0], hd[4 * i + 0], a0);
      a1 = fmaf(dwhh[4 * i + 1], hd[4 * i + 1], a1);
      a2 = fmaf(dwhh[4 * i + 2], hd[4 * i + 2], a2);
      a3 = fmaf(dwhh[4 * i + 3], hd[4 * i + 3], a3);
    }
    const float a = (a0 + a1) + (a2 + a3);
    const float e = __builtin_amdgcn_exp2f(am * a);
    const float act = fmaf(as, __builtin_amdgcn_rcpf(1.0f + e), ab);
    const float gi = qbcast<0>(act);
    const float gf = qbcast<1>(act);
    const float gg = qbcast<2>(act);
    const float go = qbcast<3>(act);
    cd = fmaf(gf, cd, gi * gg);
    const float h = go * tanh_fast(cd);
#pragma unroll
    for (int i = 0; i < 8; ++i) hd[i] = rdlane(h, 8 * i);
    // fused output projection y[yr] = ob + ow . hd (uniform hd -> SGPR operands)
    float y = ob;
#pragma unroll
    for (int i = 0; i < 8; ++i) y = fmaf(ow[i], hd[i], y);
    if (l < 8) outp[t * 8 + yr] = y;
  }
}

extern "C" void kernel_launch(void* const* d_in, const int* in_sizes, int n_in,
                              void* d_out, int out_size, void* d_ws, size_t ws_size,
                              hipStream_t stream) {
  const float* x    = (const float*)d_in[0];
  const float* eWih = (const float*)d_in[1];
  const float* eWhh = (const float*)d_in[2];
  const float* ebih = (const float*)d_in[3];
  const float* ebhh = (const float*)d_in[4];
  const float* dWih = (const float*)d_in[5];
  const float* dWhh = (const float*)d_in[6];
  const float* dbih = (const float*)d_in[7];
  const float* dbhh = (const float*)d_in[8];
  const float* oW   = (const float*)d_in[9];
  const float* obv  = (const float*)d_in[10];
  float* out = (float*)d_out;

  dim3 grid(NBATCH / 4);    // 1024 blocks -> 4/CU -> 16 waves/CU (4/SIMD)
  dim3 block(256);          // 4 waves; each wave = one batch element
  hipLaunchKernelGGL(lstm_ae_kernel, grid, block, 0, stream,
                     x, eWih, eWhh, ebih, ebhh, dWih, dWhh, dbih, dbhh, oW, obv, out);
}

// Round 6
// 119.418 us; speedup vs baseline: 1.7710x; 1.7710x over previous
//
#include <hip/hip_runtime.h>

typedef float f2 __attribute__((ext_vector_type(2)));

#define T_SEQ 256
#define NF 8
#define HID 16
#define NBATCH 4096

// DPP move (VALU-speed cross-lane within 16-lane rows / 4-lane quads)
template<int CTRL>
__device__ __forceinline__ float dppf(float v) {
  return __int_as_float(__builtin_amdgcn_update_dpp(0, __float_as_int(v), CTRL, 0xF, 0xF, true));
}
#define QB0 0x00      // quad_perm broadcast lane k of quad
#define QB1 0x55
#define QB2 0xAA
#define QB3 0xFF
#define ROR4  (0x120 + 4)   // row rotate by 4 (within 16-lane row)
#define ROR8  (0x120 + 8)   // == lane^8 within row (self-inverse)
#define ROR12 (0x120 + 12)

__device__ __forceinline__ f2 pkfma(f2 a, f2 b, f2 c) {
  return __builtin_elementwise_fma(a, b, c);   // v_pk_fma_f32
}
__device__ __forceinline__ float sigm(float a) {
  const float e = __builtin_amdgcn_exp2f(-1.4426950408889634f * a);
  return __builtin_amdgcn_rcpf(1.0f + e);
}
__device__ __forceinline__ float tanhf_(float a) {
  const float e = __builtin_amdgcn_exp2f(-2.8853900817779268f * a);
  return fmaf(2.0f, __builtin_amdgcn_rcpf(1.0f + e), -1.0f);
}

__global__ __launch_bounds__(256, 1)
void lstm_ae_kernel(const float* __restrict__ x,
                    const float* __restrict__ eWih, const float* __restrict__ eWhh,
                    const float* __restrict__ ebih, const float* __restrict__ ebhh,
                    const float* __restrict__ dWih, const float* __restrict__ dWhh,
                    const float* __restrict__ dbih, const float* __restrict__ dbhh,
                    const float* __restrict__ oW, const float* __restrict__ obv,
                    float* __restrict__ out) {
  const int tid = threadIdx.x;
  const int j = tid & 15;            // unit slot within 16-lane group (one elem/group)
  const int Q = j >> 2;              // quad within row
  const int elem = blockIdx.x * 16 + (tid >> 4);

  // one-time DPP rotation-direction probe: makes ror-direction assumption self-correcting.
  // probe value = row-lane id; after ROR4, wave-lane 4 holds either lane0 (dst[n]=src[n-4]) or lane8.
  const int pr = __builtin_amdgcn_update_dpp(0, j, ROR4, 0xF, 0xF, true);
  const int dir = (__builtin_amdgcn_readlane(pr, 4) == 0) ? 3 : 1;  // (Q - d) == (Q + 3d) mod 4
  // quad holding h-set d after rotation by 4d:
  const int qs1 = (Q + dir) & 3, qs2 = (Q + 2 * dir) & 3, qs3 = (Q + 3 * dir) & 3;
  int qsv[4] = {Q, qs1, qs2, qs3};

  // ---- encoder weights: lane j owns gate rows {j,16+j,32+j,48+j} (i,f,g,o);
  //      Whh columns pre-permuted to the DPP-transposed h layout ----
  f2 wx[4][4], wh[4][4][2];
  float eb[4];
#pragma unroll
  for (int g = 0; g < 4; ++g) {
    const int row = g * 16 + j;
    const f2* wp = (const f2*)(eWih + row * 8);
#pragma unroll
    for (int k = 0; k < 4; ++k) wx[g][k] = wp[k];
#pragma unroll
    for (int d = 0; d < 4; ++d)
#pragma unroll
      for (int kk = 0; kk < 2; ++kk) {
        const int col = 4 * qsv[d] + 2 * kk;
        wh[g][d][kk] = f2{eWhh[row * 16 + col], eWhh[row * 16 + col + 1]};
      }
    eb[g] = ebih[row] + ebhh[row];
  }

  f2 hp[4][2];                        // transposed h: hp[d][kk] = h[4*qsv[d]+2kk .. +1]
#pragma unroll
  for (int d = 0; d < 4; ++d) { hp[d][0] = f2{0.f, 0.f}; hp[d][1] = f2{0.f, 0.f}; }
  float c = 0.0f;

  const float4* xv = (const float4*)(x + (size_t)elem * (T_SEQ * NF));

  auto enc_step = [&](const float4 xa, const float4 xb) {
    const f2 xk[4] = { f2{xa.x, xa.y}, f2{xa.z, xa.w}, f2{xb.x, xb.y}, f2{xb.z, xb.w} };
    float a[4];
#pragma unroll
    for (int g = 0; g < 4; ++g) {
      // 3 parallel 4-deep chains: x-part (ready early) + two h-part halves
      f2 accX = f2{eb[g], 0.0f};
#pragma unroll
      for (int k = 0; k < 4; ++k) accX = pkfma(wx[g][k], xk[k], accX);
      f2 acc1 = pkfma(wh[g][0][0], hp[0][0], f2{0.f, 0.f});
      acc1 = pkfma(wh[g][0][1], hp[0][1], acc1);
      acc1 = pkfma(wh[g][1][0], hp[1][0], acc1);
      acc1 = pkfma(wh[g][1][1], hp[1][1], acc1);
      f2 acc2 = pkfma(wh[g][2][0], hp[2][0], f2{0.f, 0.f});
      acc2 = pkfma(wh[g][2][1], hp[2][1], acc2);
      acc2 = pkfma(wh[g][3][0], hp[3][0], acc2);
      acc2 = pkfma(wh[g][3][1], hp[3][1], acc2);
      const f2 s = (accX + acc1) + acc2;
      a[g] = s.x + s.y;
    }
    const float iv = sigm(a[0]);
    const float fv = sigm(a[1]);
    const float gv = tanhf_(a[2]);
    const float ov = sigm(a[3]);
    c = fmaf(fv, c, iv * gv);
    const float h = ov * tanhf_(c);
    // transpose h across the 16-lane row: 4 quad_perm + 12 row_ror (all VALU)
    const float v0 = dppf<QB0>(h), v1 = dppf<QB1>(h), v2 = dppf<QB2>(h), v3 = dppf<QB3>(h);
    hp[0][0] = f2{v0, v1};           hp[0][1] = f2{v2, v3};
    hp[1][0] = f2{dppf<ROR4>(v0),  dppf<ROR4>(v1)};  hp[1][1] = f2{dppf<ROR4>(v2),  dppf<ROR4>(v3)};
    hp[2][0] = f2{dppf<ROR8>(v0),  dppf<ROR8>(v1)};  hp[2][1] = f2{dppf<ROR8>(v2),  dppf<ROR8>(v3)};
    hp[3][0] = f2{dppf<ROR12>(v0), dppf<ROR12>(v1)}; hp[3][1] = f2{dppf<ROR12>(v2), dppf<ROR12>(v3)};
  };

  // chunk = 2 timesteps (4 float4). 3-buffer pipeline, prefetch distance 2:
  // A = chunk it (consumed now), B = chunk it+1, C = chunk it+2 (issued now).
  float4 A0 = xv[0], A1 = xv[1], A2 = xv[2], A3 = xv[3];
  float4 B0 = xv[4], B1 = xv[5], B2 = xv[6], B3 = xv[7];
  for (int it = 0; it < T_SEQ / 2; ++it) {
    int tp = it + 2; if (tp > T_SEQ / 2 - 1) tp = T_SEQ / 2 - 1;   // tail: redundant reload, no wrap
    const float4 C0 = xv[4 * tp + 0], C1 = xv[4 * tp + 1];
    const float4 C2 = xv[4 * tp + 2], C3 = xv[4 * tp + 3];
    enc_step(A0, A1);                 // timestep 2*it
    enc_step(A2, A3);                 // timestep 2*it+1
    A0 = B0; A1 = B1; A2 = B2; A3 = B3;
    B0 = C0; B1 = C1; B2 = C2; B3 = C3;
  }
  // hp = transposed h_enc

  // ---- decoder: lane j owns gate rows {j, j+16} of 32 (i:0-7 f:8-15 g:16-23 o:24-31) ----
  const int drA = j, drB = j + 16;
  float cgA, cgB;
  {
    f2 aA = f2{dbih[drA] + dbhh[drA], 0.0f};
    f2 aB = f2{dbih[drB] + dbhh[drB], 0.0f};
#pragma unroll
    for (int d = 0; d < 4; ++d)
#pragma unroll
      for (int kk = 0; kk < 2; ++kk) {
        const int col = 4 * qsv[d] + 2 * kk;
        aA = pkfma(f2{dWih[drA * 16 + col], dWih[drA * 16 + col + 1]}, hp[d][kk], aA);
        aB = pkfma(f2{dWih[drB * 16 + col], dWih[drB * 16 + col + 1]}, hp[d][kk], aB);
      }
    cgA = aA.x + aA.y;   // constant (input = h_enc every step) + bias
    cgB = aB.x + aB.y;
  }
  // decoder-hd transposed sets: s=0 -> units (4Q+k)&7, s=1 -> units (4Q+4+k)&7 (mod-8: direction-free)
  f2 dwA[2][2], dwB[2][2], owp[2][2];
  const int yr = j & 7;
#pragma unroll
  for (int s = 0; s < 2; ++s)
#pragma unroll
    for (int kk = 0; kk < 2; ++kk) {
      const int c0 = (4 * Q + 4 * s + 2 * kk) & 7;   // even, c0+1 in-range
      dwA[s][kk] = f2{dWhh[drA * 8 + c0], dWhh[drA * 8 + c0 + 1]};
      dwB[s][kk] = f2{dWhh[drB * 8 + c0], dWhh[drB * 8 + c0 + 1]};
      owp[s][kk] = f2{oW[yr * 8 + c0], oW[yr * 8 + c0 + 1]};
    }
  const float yb = obv[yr];
  const bool loA = (j < 8);           // rowA=i, rowB=g (tanh) ; else rowA=f, rowB=o
  const float mB = loA ? -2.8853900817779268f : -1.4426950408889634f;
  const float sB = loA ? 2.0f : 1.0f;
  const float bBc = loA ? -1.0f : 0.0f;

  f2 dp[2][2];
#pragma unroll
  for (int s = 0; s < 2; ++s) { dp[s][0] = f2{0.f, 0.f}; dp[s][1] = f2{0.f, 0.f}; }
  float cd = 0.0f;
  float* const outp = out + (size_t)elem * (T_SEQ * NF);

#pragma unroll 2
  for (int t = 0; t < T_SEQ; ++t) {
    f2 accA = f2{cgA, 0.0f}, accB = f2{cgB, 0.0f};
#pragma unroll
    for (int s = 0; s < 2; ++s) {
      accA = pkfma(dwA[s][0], dp[s][0], accA);
      accA = pkfma(dwA[s][1], dp[s][1], accA);
      accB = pkfma(dwB[s][0], dp[s][0], accB);
      accB = pkfma(dwB[s][1], dp[s][1], accB);
    }
    const float aA = accA.x + accA.y;
    const float aB = accB.x + accB.y;
    const float actA = sigm(aA);                               // i or f (always sigmoid)
    const float eB = __builtin_amdgcn_exp2f(mB * aB);
    const float actB = fmaf(sB, __builtin_amdgcn_rcpf(1.0f + eB), bBc);  // g(tanh) or o(sigm)
    const float pA = dppf<ROR8>(actA);                         // exchange with lane j^8
    const float pB = dppf<ROR8>(actB);
    const float iv = loA ? actA : pA;
    const float fv = loA ? pA : actA;
    const float gv = loA ? actB : pB;
    const float ov = loA ? pB : actB;
    cd = fmaf(fv, cd, iv * gv);
    const float h = ov * tanhf_(cd);                           // unit yr, dup on j and j+8
    // transpose hd (8 units): 4 quad_perm + 4 ror:4
    const float v0 = dppf<QB0>(h), v1 = dppf<QB1>(h), v2 = dppf<QB2>(h), v3 = dppf<QB3>(h);
    dp[0][0] = f2{v0, v1};  dp[0][1] = f2{v2, v3};
    dp[1][0] = f2{dppf<ROR4>(v0), dppf<ROR4>(v1)};
    dp[1][1] = f2{dppf<ROR4>(v2), dppf<ROR4>(v3)};
    // fused output projection y[yr] = out_b + oW[yr,:] . h_t
    f2 ya = f2{yb, 0.0f};
#pragma unroll
    for (int s = 0; s < 2; ++s) {
      ya = pkfma(owp[s][0], dp[s][0], ya);
      ya = pkfma(owp[s][1], dp[s][1], ya);
    }
    if (loA) outp[t * 8 + j] = ya.x + ya.y;
  }
}

extern "C" void kernel_launch(void* const* d_in, const int* in_sizes, int n_in,
                              void* d_out, int out_size, void* d_ws, size_t ws_size,
                              hipStream_t stream) {
  const float* x    = (const float*)d_in[0];
  const float* eWih = (const float*)d_in[1];
  const float* eWhh = (const float*)d_in[2];
  const float* ebih = (const float*)d_in[3];
  const float* ebhh = (const float*)d_in[4];
  const float* dWih = (const float*)d_in[5];
  const float* dWhh = (const float*)d_in[6];
  const float* dbih = (const float*)d_in[7];
  const float* dbhh = (const float*)d_in[8];
  const float* oW   = (const float*)d_in[9];
  const float* obv  = (const float*)d_in[10];
  float* out = (float*)d_out;

  dim3 grid(NBATCH / 16);   // 256 blocks -> 1/CU; 1024 waves -> 1/SIMD on every SIMD
  dim3 block(256);          // 4 waves; each 16-lane group = one batch element
  hipLaunchKernelGGL(lstm_ae_kernel, grid, block, 0, stream,
                     x, eWih, eWhh, ebih, ebhh, dWih, dWhh, dbih, dbhh, oW, obv, out);
}